// Round 1
// baseline (345.536 us; speedup 1.0000x reference)
//
#include <hip/hip_runtime.h>

#define NE 8
#define NTOK 8192
#define DIN 2048
#define DOUT 4096
#define BM 128
#define BN 128
#define BK 32
#define NTN (DOUT / BN)          // 32 n-tiles
#define MAXMT (NTOK / BM + NE)   // 72 worst-case m-tiles

typedef __attribute__((ext_vector_type(4))) float f32x4;
typedef __attribute__((ext_vector_type(8))) short short8;
typedef __attribute__((ext_vector_type(8))) __bf16 bf16x8;

__device__ __forceinline__ short8 cvt_bf16x8(f32x4 a, f32x4 b) {
  bf16x8 v;
  v[0] = (__bf16)a[0]; v[1] = (__bf16)a[1];
  v[2] = (__bf16)a[2]; v[3] = (__bf16)a[3];
  v[4] = (__bf16)b[0]; v[5] = (__bf16)b[1];
  v[6] = (__bf16)b[2]; v[7] = (__bf16)b[3];
  return __builtin_bit_cast(short8, v);
}

__device__ __forceinline__ void gload_lds16(const float* g, float* l) {
  __builtin_amdgcn_global_load_lds(
      (const __attribute__((address_space(1))) void*)g,
      (__attribute__((address_space(3))) void*)l,
      16, 0, 0);
}

__global__ __launch_bounds__(256, 2)
void moe_grouped_gemm(const float* __restrict__ x,
                      const float* __restrict__ w,
                      const int* __restrict__ ef,
                      float* __restrict__ out) {
  __shared__ float As[BM * BK];   // 16 KB fp32 A tile
  __shared__ float Bs[BN * BK];   // 16 KB fp32 B tile (W rows, K-major)

  const int tid  = threadIdx.x;
  const int lane = tid & 63;
  const int wv   = tid >> 6;      // wave 0..3

  const int bid = blockIdx.x;
  const int nt  = bid % NTN;      // consecutive blocks share the A panel (m-tile)
  const int mt  = bid / NTN;

  // map global m-tile -> (expert, row range); tokens are contiguous per expert
  int cumT = 0, cumTok = 0;
  int e = -1, rowStart = 0, lastRow = 0;
  for (int i = 0; i < NE; ++i) {
    int f = ef[i];
    int t = (f + BM - 1) / BM;
    if (mt < cumT + t) {
      e = i;
      rowStart = cumTok + (mt - cumT) * BM;
      lastRow  = cumTok + f - 1;
      break;
    }
    cumT += t;
    cumTok += f;
  }
  if (e < 0) return;   // beyond actual tile count (uniform across block)

  const float* wexp = w + (size_t)e * DOUT * DIN;
  const int ncol0 = nt * BN;

  // staging geometry: per issue i, segment seg = i*4 + wv holds 8 rows;
  // lane covers flat f32 idx seg*256 + lane*4  (row = seg*8 + lane/8, col = (lane&7)*4)
  const int srow = lane >> 3;
  const int scol = (lane & 7) * 4;

  f32x4 acc[4][4];
#pragma unroll
  for (int m = 0; m < 4; ++m)
#pragma unroll
    for (int n = 0; n < 4; ++n)
      acc[m][n] = f32x4{0.f, 0.f, 0.f, 0.f};

  const int wr = (wv >> 1) * 64;  // wave's 64x64 sub-tile
  const int wc = (wv & 1) * 64;

  for (int k0 = 0; k0 < DIN; k0 += BK) {
    __syncthreads();  // previous tile fully consumed
#pragma unroll
    for (int i = 0; i < 4; ++i) {
      const int seg = i * 4 + wv;
      int arow = rowStart + seg * 8 + srow;
      arow = arow > lastRow ? lastRow : arow;  // clamp ragged M (outputs guarded later)
      gload_lds16(x + (size_t)arow * DIN + k0 + scol, &As[seg * 256]);
      const int brow = ncol0 + seg * 8 + srow;
      gload_lds16(wexp + (size_t)brow * DIN + k0 + scol, &Bs[seg * 256]);
    }
    __syncthreads();  // compiler drains vmcnt before barrier

    const int kb = (lane >> 4) * 8;  // k-offset of this lane's fragment
    const int fr = lane & 15;        // row/col within fragment
    short8 afr[4], bfr[4];
#pragma unroll
    for (int m = 0; m < 4; ++m) {
      const f32x4* p = reinterpret_cast<const f32x4*>(&As[(wr + m * 16 + fr) * BK + kb]);
      afr[m] = cvt_bf16x8(p[0], p[1]);
    }
#pragma unroll
    for (int n = 0; n < 4; ++n) {
      const f32x4* p = reinterpret_cast<const f32x4*>(&Bs[(wc + n * 16 + fr) * BK + kb]);
      bfr[n] = cvt_bf16x8(p[0], p[1]);
    }
#pragma unroll
    for (int m = 0; m < 4; ++m)
#pragma unroll
      for (int n = 0; n < 4; ++n)
        acc[m][n] = __builtin_amdgcn_mfma_f32_16x16x32_bf16(afr[m], bfr[n], acc[m][n], 0, 0, 0);
  }

  // epilogue: C/D layout col = lane&15, row = (lane>>4)*4 + j  [m89-verified]
  const int fr = lane & 15;
  const int rq = (lane >> 4) * 4;
#pragma unroll
  for (int m = 0; m < 4; ++m) {
#pragma unroll
    for (int j = 0; j < 4; ++j) {
      const int grow = rowStart + wr + m * 16 + rq + j;
      if (grow <= lastRow) {
        float* op = out + (size_t)grow * DOUT + ncol0 + wc;
#pragma unroll
        for (int n = 0; n < 4; ++n)
          op[n * 16 + fr] = acc[m][n][j];
      }
    }
  }
}

extern "C" void kernel_launch(void* const* d_in, const int* in_sizes, int n_in,
                              void* d_out, int out_size, void* d_ws, size_t ws_size,
                              hipStream_t stream) {
  const float* x  = (const float*)d_in[0];
  const float* w  = (const float*)d_in[1];
  const int*   ef = (const int*)d_in[2];
  float* out = (float*)d_out;
  (void)d_ws; (void)ws_size; (void)in_sizes; (void)n_in; (void)out_size;

  moe_grouped_gemm<<<dim3(MAXMT * NTN), dim3(256), 0, stream>>>(x, w, ef, out);
}

// Round 2
// 311.051 us; speedup vs baseline: 1.1109x; 1.1109x over previous
//
#include <hip/hip_runtime.h>

#define NE 8
#define NTOK 8192
#define DIN 2048
#define DOUT 4096
#define BM 128
#define BN 128
#define NTN (DOUT / BN)          // 32 n-tiles
#define MAXMT (NTOK / BM + NE)   // 72 worst-case m-tiles (2304 blocks, %8==0)

typedef __attribute__((ext_vector_type(4))) float f32x4;
typedef __attribute__((ext_vector_type(8))) short short8;
typedef __attribute__((ext_vector_type(8))) __bf16 bf16x8;

__device__ __forceinline__ void gload_lds16(const void* g, void* l) {
  __builtin_amdgcn_global_load_lds(
      (const __attribute__((address_space(1))) void*)g,
      (__attribute__((address_space(3))) void*)l,
      16, 0, 0);
}

// ---------------- fp32 -> bf16 conversion pass (BW-bound) ----------------
__global__ void cvt_f32_bf16(const float* __restrict__ in,
                             __bf16* __restrict__ out, int n8) {
  const int stride = gridDim.x * blockDim.x;
  for (int i = blockIdx.x * blockDim.x + threadIdx.x; i < n8; i += stride) {
    const f32x4* p = reinterpret_cast<const f32x4*>(in + (size_t)i * 8);
    f32x4 a = p[0], b = p[1];
    bf16x8 v;
    v[0] = (__bf16)a[0]; v[1] = (__bf16)a[1];
    v[2] = (__bf16)a[2]; v[3] = (__bf16)a[3];
    v[4] = (__bf16)b[0]; v[5] = (__bf16)b[1];
    v[6] = (__bf16)b[2]; v[7] = (__bf16)b[3];
    *reinterpret_cast<bf16x8*>(out + (size_t)i * 8) = v;
  }
}

// ---------------- grouped bf16 GEMM, m97-lineage 128x128 BK=64 ----------------
__global__ __launch_bounds__(256, 2)
void moe_gemm_bf16(const __bf16* __restrict__ xb,
                   const __bf16* __restrict__ wb,
                   const int* __restrict__ ef,
                   float* __restrict__ out) {
  __shared__ __bf16 As[BM * 64];   // 16 KB, row-major [128][64]
  __shared__ __bf16 Bs[BN * 64];   // 16 KB

  const int tid  = threadIdx.x;
  const int lane = tid & 63;
  const int wv   = tid >> 6;

  // T1: XCD-aware swizzle (2304 % 8 == 0 -> bijective); consecutive tiles on
  // one XCD share the A panel (m-tile) -> x panel L2-resident.
  const int b    = blockIdx.x;
  const int tile = (b & 7) * (MAXMT * NTN / 8) + (b >> 3);
  const int nt   = tile % NTN;
  const int mt   = tile / NTN;

  // map m-tile -> (expert, row range); tokens contiguous per expert
  int cumT = 0, cumTok = 0;
  int e = -1, rowStart = 0, lastRow = 0;
  for (int i = 0; i < NE; ++i) {
    int f = ef[i];
    int t = (f + BM - 1) / BM;
    if (mt < cumT + t) {
      e = i;
      rowStart = cumTok + (mt - cumT) * BM;
      lastRow  = cumTok + f - 1;
      break;
    }
    cumT += t;
    cumTok += f;
  }
  if (e < 0) return;  // dead tile (uniform across block, before any barrier)

  const __bf16* wexp = wb + (size_t)e * DOUT * DIN;
  const int ncol0 = nt * BN;

  // staging: 16 segments x 1 KB; seg = issue*4 + wv; lane covers 16 B at
  // seg*1024 + lane*16  (row = seg*8 + lane>>3, bf16 col = (lane&7)*8)
  const int srow = lane >> 3;
  const int scol = (lane & 7) * 8;

  f32x4 acc[4][4];
#pragma unroll
  for (int m = 0; m < 4; ++m)
#pragma unroll
    for (int n = 0; n < 4; ++n)
      acc[m][n] = f32x4{0.f, 0.f, 0.f, 0.f};

  const int wr = (wv >> 1) * 64;  // wave's 64x64 output sub-tile
  const int wc = (wv & 1) * 64;
  const int fr = lane & 15;
  const int kg = lane >> 4;

  for (int k0 = 0; k0 < DIN; k0 += 64) {
    __syncthreads();  // previous tile fully consumed
#pragma unroll
    for (int i = 0; i < 4; ++i) {
      const int seg = i * 4 + wv;
      int arow = rowStart + seg * 8 + srow;
      arow = arow > lastRow ? lastRow : arow;  // clamp ragged M (C-write guarded)
      gload_lds16(xb + (size_t)arow * DIN + k0 + scol, &As[seg * 512]);
      const int brow = ncol0 + seg * 8 + srow;
      gload_lds16(wexp + (size_t)brow * DIN + k0 + scol, &Bs[seg * 512]);
    }
    __syncthreads();  // compiler drains vmcnt before barrier

    bf16x8 afr[2][4], bfr[2][4];
#pragma unroll
    for (int kk = 0; kk < 2; ++kk) {
#pragma unroll
      for (int m = 0; m < 4; ++m)
        afr[kk][m] = *reinterpret_cast<const bf16x8*>(
            &As[(wr + m * 16 + fr) * 64 + kk * 32 + kg * 8]);
#pragma unroll
      for (int n = 0; n < 4; ++n)
        bfr[kk][n] = *reinterpret_cast<const bf16x8*>(
            &Bs[(wc + n * 16 + fr) * 64 + kk * 32 + kg * 8]);
    }
#pragma unroll
    for (int kk = 0; kk < 2; ++kk)
#pragma unroll
      for (int m = 0; m < 4; ++m)
#pragma unroll
        for (int n = 0; n < 4; ++n)
          acc[m][n] = __builtin_amdgcn_mfma_f32_16x16x32_bf16(
              __builtin_bit_cast(short8, afr[kk][m]),
              __builtin_bit_cast(short8, bfr[kk][n]), acc[m][n], 0, 0, 0);
  }

  // epilogue: C/D layout col = lane&15, row = (lane>>4)*4 + j  [m89-verified]
  const int rq = (lane >> 4) * 4;
#pragma unroll
  for (int m = 0; m < 4; ++m) {
#pragma unroll
    for (int j = 0; j < 4; ++j) {
      const int grow = rowStart + wr + m * 16 + rq + j;
      if (grow <= lastRow) {
        float* op = out + (size_t)grow * DOUT + ncol0 + wc;
#pragma unroll
        for (int n = 0; n < 4; ++n)
          op[n * 16 + fr] = acc[m][n][j];
      }
    }
  }
}

// ---------------- fallback: R1 fused fp32-staging kernel ----------------
__device__ __forceinline__ short8 cvt_bf16x8(f32x4 a, f32x4 b) {
  bf16x8 v;
  v[0] = (__bf16)a[0]; v[1] = (__bf16)a[1];
  v[2] = (__bf16)a[2]; v[3] = (__bf16)a[3];
  v[4] = (__bf16)b[0]; v[5] = (__bf16)b[1];
  v[6] = (__bf16)b[2]; v[7] = (__bf16)b[3];
  return __builtin_bit_cast(short8, v);
}

__global__ __launch_bounds__(256, 2)
void moe_grouped_gemm_f32(const float* __restrict__ x,
                          const float* __restrict__ w,
                          const int* __restrict__ ef,
                          float* __restrict__ out) {
  __shared__ float As[BM * 32];
  __shared__ float Bs[BN * 32];
  const int tid = threadIdx.x, lane = tid & 63, wv = tid >> 6;
  const int bid = blockIdx.x, nt = bid % NTN, mt = bid / NTN;
  int cumT = 0, cumTok = 0, e = -1, rowStart = 0, lastRow = 0;
  for (int i = 0; i < NE; ++i) {
    int f = ef[i], t = (f + BM - 1) / BM;
    if (mt < cumT + t) { e = i; rowStart = cumTok + (mt - cumT) * BM; lastRow = cumTok + f - 1; break; }
    cumT += t; cumTok += f;
  }
  if (e < 0) return;
  const float* wexp = w + (size_t)e * DOUT * DIN;
  const int ncol0 = nt * BN;
  const int srow = lane >> 3, scol = (lane & 7) * 4;
  f32x4 acc[4][4];
#pragma unroll
  for (int m = 0; m < 4; ++m)
#pragma unroll
    for (int n = 0; n < 4; ++n) acc[m][n] = f32x4{0.f, 0.f, 0.f, 0.f};
  const int wr = (wv >> 1) * 64, wc = (wv & 1) * 64;
  for (int k0 = 0; k0 < DIN; k0 += 32) {
    __syncthreads();
#pragma unroll
    for (int i = 0; i < 4; ++i) {
      const int seg = i * 4 + wv;
      int arow = rowStart + seg * 8 + srow;
      arow = arow > lastRow ? lastRow : arow;
      gload_lds16(x + (size_t)arow * DIN + k0 + scol, &As[seg * 256]);
      const int brow = ncol0 + seg * 8 + srow;
      gload_lds16(wexp + (size_t)brow * DIN + k0 + scol, &Bs[seg * 256]);
    }
    __syncthreads();
    const int kb = (lane >> 4) * 8, fr = lane & 15;
    short8 afr[4], bfr[4];
#pragma unroll
    for (int m = 0; m < 4; ++m) {
      const f32x4* p = reinterpret_cast<const f32x4*>(&As[(wr + m * 16 + fr) * 32 + kb]);
      afr[m] = cvt_bf16x8(p[0], p[1]);
    }
#pragma unroll
    for (int n = 0; n < 4; ++n) {
      const f32x4* p = reinterpret_cast<const f32x4*>(&Bs[(wc + n * 16 + fr) * 32 + kb]);
      bfr[n] = cvt_bf16x8(p[0], p[1]);
    }
#pragma unroll
    for (int m = 0; m < 4; ++m)
#pragma unroll
      for (int n = 0; n < 4; ++n)
        acc[m][n] = __builtin_amdgcn_mfma_f32_16x16x32_bf16(afr[m], bfr[n], acc[m][n], 0, 0, 0);
  }
  const int fr = lane & 15, rq = (lane >> 4) * 4;
#pragma unroll
  for (int m = 0; m < 4; ++m)
#pragma unroll
    for (int j = 0; j < 4; ++j) {
      const int grow = rowStart + wr + m * 16 + rq + j;
      if (grow <= lastRow) {
        float* op = out + (size_t)grow * DOUT + ncol0 + wc;
#pragma unroll
        for (int n = 0; n < 4; ++n) op[n * 16 + fr] = acc[m][n][j];
      }
    }
}

extern "C" void kernel_launch(void* const* d_in, const int* in_sizes, int n_in,
                              void* d_out, int out_size, void* d_ws, size_t ws_size,
                              hipStream_t stream) {
  const float* x  = (const float*)d_in[0];
  const float* w  = (const float*)d_in[1];
  const int*   ef = (const int*)d_in[2];
  float* out = (float*)d_out;
  (void)in_sizes; (void)n_in; (void)out_size;

  const size_t nx = (size_t)NTOK * DIN;          // 16.8M
  const size_t nw = (size_t)NE * DOUT * DIN;     // 67.1M
  const size_t need = (nx + nw) * sizeof(__bf16);  // 160 MiB

  if (ws_size >= need) {
    __bf16* xb = (__bf16*)d_ws;
    __bf16* wbuf = xb + nx;
    {
      int n8 = (int)(nx / 8);
      int grid = (n8 + 255) / 256; if (grid > 2048) grid = 2048;
      cvt_f32_bf16<<<dim3(grid), dim3(256), 0, stream>>>(x, xb, n8);
    }
    {
      int n8 = (int)(nw / 8);
      int grid = (n8 + 255) / 256; if (grid > 4096) grid = 4096;
      cvt_f32_bf16<<<dim3(grid), dim3(256), 0, stream>>>(w, wbuf, n8);
    }
    moe_gemm_bf16<<<dim3(MAXMT * NTN), dim3(256), 0, stream>>>(xb, wbuf, ef, out);
  } else {
    moe_grouped_gemm_f32<<<dim3(MAXMT * NTN), dim3(256), 0, stream>>>(x, w, ef, out);
  }
}

// Round 3
// 274.470 us; speedup vs baseline: 1.2589x; 1.1333x over previous
//
#include <hip/hip_runtime.h>

#define NE 8
#define NTOK 8192
#define DIN 2048
#define DOUT 4096

// ---- 256x256, BK=64, 8-wave, 8-phase geometry ----
#define BM 256
#define BN 256
#define BK 64
#define NTN (DOUT / BN)          // 16 n-tiles
#define MAXMT (NTOK / BM + NE)   // 40 worst-case m-tiles -> 640 blocks (%8==0)
#define NKT (DIN / BK)           // 32 K-tiles
#define LDS_BUF 65536            // one double-buffer half: A 32K + B 32K
#define BOFF 32768               // B offset inside a buffer
#define GRAN 8192                // granule = 64 rows x 64 cols x 2B

typedef __attribute__((ext_vector_type(4))) float f32x4;
typedef __attribute__((ext_vector_type(8))) short short8;
typedef __attribute__((ext_vector_type(8))) __bf16 bf16x8;

__device__ __forceinline__ void gload_lds16(const void* g, void* l) {
  __builtin_amdgcn_global_load_lds(
      (const __attribute__((address_space(1))) void*)g,
      (__attribute__((address_space(3))) void*)l,
      16, 0, 0);
}

// ---------------- fp32 -> bf16 conversion pass (BW-bound, at floor) ----------------
__global__ void cvt_f32_bf16(const float* __restrict__ in,
                             __bf16* __restrict__ out, int n8) {
  const int stride = gridDim.x * blockDim.x;
  for (int i = blockIdx.x * blockDim.x + threadIdx.x; i < n8; i += stride) {
    const f32x4* p = reinterpret_cast<const f32x4*>(in + (size_t)i * 8);
    f32x4 a = p[0], b = p[1];
    bf16x8 v;
    v[0] = (__bf16)a[0]; v[1] = (__bf16)a[1];
    v[2] = (__bf16)a[2]; v[3] = (__bf16)a[3];
    v[4] = (__bf16)b[0]; v[5] = (__bf16)b[1];
    v[6] = (__bf16)b[2]; v[7] = (__bf16)b[3];
    *reinterpret_cast<bf16x8*>(out + (size_t)i * 8) = v;
  }
}

// LDS read with T2 XOR swizzle: element (row, colbyte cb) lives at
// row*128 + (cb ^ ((row&7)<<4)).  Staging pre-applies the same involution
// to the GLOBAL source (linear gload_lds dest) — rule #21 both-sides.
__device__ __forceinline__ bf16x8 lds_rd(const char* p) {
  return *reinterpret_cast<const bf16x8*>(p);
}

__device__ __forceinline__ f32x4 mfma16(bf16x8 a, bf16x8 b, f32x4 c) {
  return __builtin_amdgcn_mfma_f32_16x16x32_bf16(
      __builtin_bit_cast(short8, a), __builtin_bit_cast(short8, b), c, 0, 0, 0);
}

// ---------------- grouped bf16 GEMM: 256^2 8-phase (T1+T2+T3+T4+T5) ----------------
__global__ __launch_bounds__(512, 2)
void moe_gemm_bf16_8ph(const __bf16* __restrict__ xb,
                       const __bf16* __restrict__ wb,
                       const int* __restrict__ ef,
                       float* __restrict__ out) {
  __shared__ __attribute__((aligned(16))) char lds[2 * LDS_BUF];  // 128 KiB

  const int tid  = threadIdx.x;
  const int lane = tid & 63;
  const int wv   = tid >> 6;   // 0..7
  const int wm   = wv >> 2;    // 0..1 (M split)
  const int wn   = wv & 3;     // 0..3 (N split)
  const int fr   = lane & 15;
  const int kg   = lane >> 4;

  // T1: bijective XCD swizzle (640 % 8 == 0)
  const int b    = blockIdx.x;
  const int tile = (b & 7) * (MAXMT * NTN / 8) + (b >> 3);
  const int nt   = tile % NTN;
  const int mt   = tile / NTN;

  // m-tile -> (expert, row range); tokens contiguous per expert
  int cumT = 0, cumTok = 0;
  int e = -1, rowStart = 0, lastRow = 0;
  for (int i = 0; i < NE; ++i) {
    int f = ef[i];
    int t = (f + BM - 1) / BM;
    if (mt < cumT + t) {
      e = i;
      rowStart = cumTok + (mt - cumT) * BM;
      lastRow  = cumTok + f - 1;
      break;
    }
    cumT += t;
    cumTok += f;
  }
  if (e < 0) return;  // dead tile, uniform across block, before any barrier

  const __bf16* wexp = wb + (size_t)e * DOUT * DIN;
  const int ncol0 = nt * BN;

  // staging geometry: granule j = 64 rows x 64 cols; wave wv covers rows
  // wv*8..wv*8+7 (1 KB, HW dest = uniform base + lane*16). Source column
  // slot is pre-swizzled so that swizzled READS return linear data.
  const int srow  = wv * 8 + (lane >> 3);       // LDS row within granule
  const int sslot = (lane & 7) ^ (lane >> 3);   // inverse-swizzled 16B slot
  const __bf16* aSrc[4];
  const __bf16* bSrc[4];
#pragma unroll
  for (int j = 0; j < 4; ++j) {
    int ar = rowStart + j * 64 + srow;
    ar = ar > lastRow ? lastRow : ar;           // clamp ragged M (C guarded)
    aSrc[j] = xb + (size_t)ar * DIN + sslot * 8;
    int br = ncol0 + j * 64 + srow;
    bSrc[j] = wexp + (size_t)br * DIN + sslot * 8;
  }

#define STA(bufi, j, k0) gload_lds16(aSrc[j] + (k0), lds + (bufi)*LDS_BUF + (j)*GRAN + wv*1024)
#define STB(bufi, j, k0) gload_lds16(bSrc[j] + (k0), lds + (bufi)*LDS_BUF + BOFF + (j)*GRAN + wv*1024)
#define LDA(bufi, row, cb) lds_rd(lds + (bufi)*LDS_BUF + (((row)*128 + ((cb) ^ (((row)&7)<<4)))))
#define LDB(bufi, row, cb) lds_rd(lds + (bufi)*LDS_BUF + BOFF + (((row)*128 + ((cb) ^ (((row)&7)<<4)))))

  f32x4 acc[8][4];
#pragma unroll
  for (int m = 0; m < 8; ++m)
#pragma unroll
    for (int n = 0; n < 4; ++n)
      acc[m][n] = f32x4{0.f, 0.f, 0.f, 0.f};

  // ---- prologue: tile0 full -> buf0; tile1 minus A g1,g3 -> buf1 ----
  STB(0, 0, 0);  STB(0, 1, 0);  STA(0, 0, 0);  STA(0, 2, 0);
  STB(0, 2, 0);  STB(0, 3, 0);  STA(0, 1, 0);  STA(0, 3, 0);
  STB(1, 0, BK); STB(1, 1, BK); STA(1, 0, BK); STA(1, 2, BK);
  STB(1, 2, BK); STB(1, 3, BK);
  asm volatile("s_waitcnt vmcnt(6)" ::: "memory");  // tile0 landed
  __builtin_amdgcn_s_barrier();

  for (int t = 0; t < NKT; ++t) {
    const int buf = t & 1;
    const int kst = (t + 2) * BK;  // k0 of tile t+2 (same-parity buffer)
    bf16x8 bfr[2][4];

    // ---------- phase 0: B all + A quadrant 0; stage A g1,g3 of t+1 ----------
#pragma unroll
    for (int kk = 0; kk < 2; ++kk)
#pragma unroll
      for (int nn = 0; nn < 4; ++nn)
        bfr[kk][nn] = LDB(buf, wn * 64 + nn * 16 + fr, kk * 64 + kg * 16);
    {
      bf16x8 a0[2][2];
#pragma unroll
      for (int kk = 0; kk < 2; ++kk)
#pragma unroll
        for (int i = 0; i < 2; ++i)
          a0[kk][i] = LDA(buf, wm * 128 + i * 16 + fr, kk * 64 + kg * 16);
      if (t + 1 < NKT) { STA(buf ^ 1, 1, (t + 1) * BK); STA(buf ^ 1, 3, (t + 1) * BK); }
      __builtin_amdgcn_s_barrier();
      asm volatile("s_waitcnt lgkmcnt(0)" ::: "memory");
      __builtin_amdgcn_s_setprio(1);
#pragma unroll
      for (int kk = 0; kk < 2; ++kk)
#pragma unroll
        for (int i = 0; i < 2; ++i)
#pragma unroll
          for (int nn = 0; nn < 4; ++nn)
            acc[i][nn] = mfma16(a0[kk][i], bfr[kk][nn], acc[i][nn]);
      __builtin_amdgcn_s_setprio(0);
      __builtin_amdgcn_s_barrier();
    }

    // ---------- phases 1..3: A quadrant p; stage tile t+2 granules ----------
#pragma unroll
    for (int p = 1; p < 4; ++p) {
      bf16x8 ap[2][2];
#pragma unroll
      for (int kk = 0; kk < 2; ++kk)
#pragma unroll
        for (int i = 0; i < 2; ++i)
          ap[kk][i] = LDA(buf, wm * 128 + (p * 2 + i) * 16 + fr, kk * 64 + kg * 16);
      if (t + 2 < NKT) {
        if (p == 1) { STB(buf, 0, kst); STB(buf, 1, kst); }  // B free since ph0
        if (p == 2) { STA(buf, 0, kst); STA(buf, 2, kst); }  // A g0,g2 free after ph1
        if (p == 3) { STB(buf, 2, kst); STB(buf, 3, kst); }
      }
      __builtin_amdgcn_s_barrier();
      asm volatile("s_waitcnt lgkmcnt(0)" ::: "memory");
      __builtin_amdgcn_s_setprio(1);
#pragma unroll
      for (int kk = 0; kk < 2; ++kk)
#pragma unroll
        for (int i = 0; i < 2; ++i)
#pragma unroll
          for (int nn = 0; nn < 4; ++nn)
            acc[p * 2 + i][nn] = mfma16(ap[kk][i], bfr[kk][nn], acc[p * 2 + i][nn]);
      __builtin_amdgcn_s_setprio(0);
      if (p == 3) {
        // counted vmcnt once per K-tile (T4): keep 6 loads (tile t+2) in flight;
        // guarantees tile t+1 (incl. its A g1,g3 issued at phase t.0) landed.
        if (t + 2 < NKT)      { asm volatile("s_waitcnt vmcnt(6)" ::: "memory"); }
        else if (t + 1 < NKT) { asm volatile("s_waitcnt vmcnt(0)" ::: "memory"); }
      }
      __builtin_amdgcn_s_barrier();
    }
  }

  // ---- epilogue: C/D layout col = lane&15, row = (lane>>4)*4 + j ----
  const int rq = (lane >> 4) * 4;
#pragma unroll
  for (int mm = 0; mm < 8; ++mm) {
#pragma unroll
    for (int j = 0; j < 4; ++j) {
      const int grow = rowStart + wm * 128 + mm * 16 + rq + j;
      if (grow <= lastRow) {
        float* op = out + (size_t)grow * DOUT + ncol0 + wn * 64;
#pragma unroll
        for (int nn = 0; nn < 4; ++nn)
          op[nn * 16 + fr] = acc[mm][nn][j];
      }
    }
  }
#undef STA
#undef STB
#undef LDA
#undef LDB
}

// ---------------- fallback: fused fp32-staging kernel (R1, verified) ----------------
__device__ __forceinline__ short8 cvt_bf16x8(f32x4 a, f32x4 b) {
  bf16x8 v;
  v[0] = (__bf16)a[0]; v[1] = (__bf16)a[1];
  v[2] = (__bf16)a[2]; v[3] = (__bf16)a[3];
  v[4] = (__bf16)b[0]; v[5] = (__bf16)b[1];
  v[6] = (__bf16)b[2]; v[7] = (__bf16)b[3];
  return __builtin_bit_cast(short8, v);
}

__global__ __launch_bounds__(256, 2)
void moe_grouped_gemm_f32(const float* __restrict__ x,
                          const float* __restrict__ w,
                          const int* __restrict__ ef,
                          float* __restrict__ out) {
  __shared__ float As[128 * 32];
  __shared__ float Bs[128 * 32];
  const int tid = threadIdx.x, lane = tid & 63, wv = tid >> 6;
  const int bid = blockIdx.x, nt = bid % 32, mt = bid / 32;
  int cumT = 0, cumTok = 0, e = -1, rowStart = 0, lastRow = 0;
  for (int i = 0; i < NE; ++i) {
    int f = ef[i], t = (f + 127) / 128;
    if (mt < cumT + t) { e = i; rowStart = cumTok + (mt - cumT) * 128; lastRow = cumTok + f - 1; break; }
    cumT += t; cumTok += f;
  }
  if (e < 0) return;
  const float* wexp = w + (size_t)e * DOUT * DIN;
  const int ncol0 = nt * 128;
  const int srow = lane >> 3, scol = (lane & 7) * 4;
  f32x4 acc[4][4];
#pragma unroll
  for (int m = 0; m < 4; ++m)
#pragma unroll
    for (int n = 0; n < 4; ++n) acc[m][n] = f32x4{0.f, 0.f, 0.f, 0.f};
  const int wr = (wv >> 1) * 64, wc = (wv & 1) * 64;
  for (int k0 = 0; k0 < DIN; k0 += 32) {
    __syncthreads();
#pragma unroll
    for (int i = 0; i < 4; ++i) {
      const int seg = i * 4 + wv;
      int arow = rowStart + seg * 8 + srow;
      arow = arow > lastRow ? lastRow : arow;
      gload_lds16(x + (size_t)arow * DIN + k0 + scol, &As[seg * 256]);
      const int brow = ncol0 + seg * 8 + srow;
      gload_lds16(wexp + (size_t)brow * DIN + k0 + scol, &Bs[seg * 256]);
    }
    __syncthreads();
    const int kb = (lane >> 4) * 8, fr = lane & 15;
    short8 afr[4], bfr[4];
#pragma unroll
    for (int m = 0; m < 4; ++m) {
      const f32x4* p = reinterpret_cast<const f32x4*>(&As[(wr + m * 16 + fr) * 32 + kb]);
      afr[m] = cvt_bf16x8(p[0], p[1]);
    }
#pragma unroll
    for (int n = 0; n < 4; ++n) {
      const f32x4* p = reinterpret_cast<const f32x4*>(&Bs[(wc + n * 16 + fr) * 32 + kb]);
      bfr[n] = cvt_bf16x8(p[0], p[1]);
    }
#pragma unroll
    for (int m = 0; m < 4; ++m)
#pragma unroll
      for (int n = 0; n < 4; ++n)
        acc[m][n] = __builtin_amdgcn_mfma_f32_16x16x32_bf16(afr[m], bfr[n], acc[m][n], 0, 0, 0);
  }
  const int fr = lane & 15, rq = (lane >> 4) * 4;
#pragma unroll
  for (int m = 0; m < 4; ++m)
#pragma unroll
    for (int j = 0; j < 4; ++j) {
      const int grow = rowStart + wr + m * 16 + rq + j;
      if (grow <= lastRow) {
        float* op = out + (size_t)grow * DOUT + ncol0 + wc;
#pragma unroll
        for (int n = 0; n < 4; ++n) op[n * 16 + fr] = acc[m][n][j];
      }
    }
}

extern "C" void kernel_launch(void* const* d_in, const int* in_sizes, int n_in,
                              void* d_out, int out_size, void* d_ws, size_t ws_size,
                              hipStream_t stream) {
  const float* x  = (const float*)d_in[0];
  const float* w  = (const float*)d_in[1];
  const int*   ef = (const int*)d_in[2];
  float* out = (float*)d_out;
  (void)in_sizes; (void)n_in; (void)out_size;

  const size_t nx = (size_t)NTOK * DIN;            // 16.8M elems
  const size_t nw = (size_t)NE * DOUT * DIN;       // 67.1M elems
  const size_t need = (nx + nw) * sizeof(__bf16);  // 160 MiB

  if (ws_size >= need) {
    __bf16* xb = (__bf16*)d_ws;
    __bf16* wbuf = xb + nx;
    {
      int n8 = (int)(nx / 8);
      int grid = (n8 + 255) / 256; if (grid > 2048) grid = 2048;
      cvt_f32_bf16<<<dim3(grid), dim3(256), 0, stream>>>(x, xb, n8);
    }
    {
      int n8 = (int)(nw / 8);
      int grid = (n8 + 255) / 256; if (grid > 4096) grid = 4096;
      cvt_f32_bf16<<<dim3(grid), dim3(256), 0, stream>>>(w, wbuf, n8);
    }
    moe_gemm_bf16_8ph<<<dim3(MAXMT * NTN), dim3(512), 0, stream>>>(xb, wbuf, ef, out);
  } else {
    moe_grouped_gemm_f32<<<dim3((NTOK / 128 + NE) * 32), dim3(256), 0, stream>>>(x, w, ef, out);
  }
}